// Round 11
// baseline (227.367 us; speedup 1.0000x reference)
//
#include <hip/hip_runtime.h>
#include <math.h>

// Problem dims: B=8, N=512, T=64, D=128, E=32, M=3, BN=4096
// ws layout (float offsets)
#define OFF_QN     768        // 96*128 = 12288
#define OFF_H      13056      // 4096*128
#define OFF_PROBS  537344     // 24
#define OFF_HV     537376     // 4096
#define OFF_SCORES 541472     // 768*512
#define OFF_HMIX   934688     // 8*32*512 = 131072
#define OFF_SHI    1115168    // 24576 floats (spaceW hi, bf16)
#define OFF_SLO    1139744    // 24576 floats (spaceW lo, bf16)
#define OFF_STATS  1164320    // 256 blocks * 256 floats
#define OFF_EV     1229856    // 256

typedef short bf16x8 __attribute__((ext_vector_type(8)));
typedef float f32x4 __attribute__((ext_vector_type(4)));

union U8 { unsigned short s[8]; bf16x8 v; uint4 u4; };

__device__ __forceinline__ unsigned short bf16_rtn(float f) {
  unsigned int u = __float_as_uint(f);
  return (unsigned short)((u + 0x7FFFu + ((u >> 16) & 1u)) >> 16);
}
__device__ __forceinline__ float bf16_f(unsigned short h) {
  return __uint_as_float(((unsigned int)h) << 16);
}
__device__ __forceinline__ void split8_rtn(const float* v, bf16x8* hi, bf16x8* lo) {
  U8 a, b;
#pragma unroll
  for (int j = 0; j < 8; ++j) {
    unsigned short h = bf16_rtn(v[j]);
    a.s[j] = h;
    b.s[j] = bf16_rtn(v[j] - bf16_f(h));
  }
  *hi = a.v; *lo = b.v;
}

// ---------------------------------------------------------------------------
// GRU, fully self-contained (prep absorbed non-redundantly):
//  - u/c: cooperative wave-per-row dots into LDS (coalesced)
//  - W_hh B-fragments: split in registers from global fp32
//  - spaceW hi/lo split: coalesced 192-elem slice per block
//  - qn rows (blocks 0..95, wave 1), ev zero (block 1), Hmix zero slice,
//    stats partials.
// 256 blocks x 512 threads, 16 seqs/block, R5/R10-verified main loop.
// ---------------------------------------------------------------------------
__global__ __launch_bounds__(512, 2) void gru_kernel(const float* __restrict__ x,
                                                     const float* __restrict__ Wih,
                                                     const float* __restrict__ projW,
                                                     const float* __restrict__ projb,
                                                     const float* __restrict__ bih,
                                                     const float* __restrict__ Whh,
                                                     const float* __restrict__ bhh,
                                                     const float* __restrict__ outW,
                                                     const float* __restrict__ spaceW,
                                                     const float* __restrict__ queries,
                                                     float* __restrict__ ws) {
  __shared__ __align__(16) unsigned short hHi[2][16 * 17 * 8];
  __shared__ __align__(16) unsigned short hLo[2][16 * 17 * 8];
  __shared__ float xsAll[16 * 65];
  __shared__ float hFin[16 * 132];
  __shared__ float ucS[768];   // u[384] | c[384]

  const int tid = threadIdx.x, wave = tid >> 6, lane = tid & 63;
  const int q = lane >> 4, s15 = lane & 15;
  const int d = wave * 16 + s15;

  // ---- absorbed one-time prep (cheap, coalesced) ----
  {
    float4 z4 = make_float4(0.f, 0.f, 0.f, 0.f);
    float4* hm4 = (float4*)(ws + OFF_HMIX);
    if (tid < 128) hm4[blockIdx.x * 128 + tid] = z4;     // Hmix zero slice
    if (tid < 192) {                                      // spaceW split slice
      int i = blockIdx.x * 192 + tid;
      float w = spaceW[i];
      unsigned short hi = bf16_rtn(w);
      ((unsigned short*)(ws + OFF_SHI))[i] = hi;
      ((unsigned short*)(ws + OFF_SLO))[i] = bf16_rtn(w - bf16_f(hi));
    }
    if (blockIdx.x < 96 && wave == 1) {                   // qn row
      const float* qrow = queries + blockIdx.x * 128;
      float v0 = qrow[lane], v1 = qrow[64 + lane];
      float ss = v0 * v0 + v1 * v1;
      for (int off = 32; off; off >>= 1) ss += __shfl_xor(ss, off);
      float inv = 1.f / fmaxf(sqrtf(ss), 1e-12f);
      ws[OFF_QN + blockIdx.x * 128 + lane] = v0 * inv;
      ws[OFF_QN + blockIdx.x * 128 + 64 + lane] = v1 * inv;
    }
    if (blockIdx.x == 1 && tid < 256) ws[OFF_EV + tid] = 0.f;  // ev zero
  }

  // ---- cooperative u/c: wave w computes rows w*48 .. w*48+47 ----
  {
    float pw0 = projW[lane], pw1 = projW[64 + lane];
    float pb0 = projb[lane], pb1 = projb[64 + lane];
    for (int i = 0; i < 48; ++i) {
      int r = wave * 48 + i;
      float w0 = Wih[r * 128 + lane], w1 = Wih[r * 128 + 64 + lane];
      float uu = w0 * pw0 + w1 * pw1;
      float cc = w0 * pb0 + w1 * pb1;
      for (int off = 32; off; off >>= 1) {
        uu += __shfl_xor(uu, off);
        cc += __shfl_xor(cc, off);
      }
      if (lane == 0) { ucS[r] = uu; ucS[384 + r] = cc + bih[r]; }
    }
  }

  // ---- W_hh B-fragments: split in registers from global fp32 ----
  bf16x8 Bhi[3][4], Blo[3][4];
#pragma unroll
  for (int t = 0; t < 3; ++t) {
    int row = (wave + 8 * t) * 16 + s15;
#pragma unroll
    for (int c = 0; c < 4; ++c) {
      float v[8];
      *(float4*)v = *(const float4*)&Whh[row * 128 + c * 32 + q * 8];
      *(float4*)(v + 4) = *(const float4*)&Whh[row * 128 + c * 32 + q * 8 + 4];
      split8_rtn(v, &Bhi[t][c], &Blo[t][c]);
    }
  }

  const int seq0 = blockIdx.x * 16;
  for (int i = tid; i < 1024; i += 512) {
    int s = i >> 6, tt = i & 63;
    int r = (seq0 + s) * 64 + tt;
    xsAll[s * 65 + tt] = x[((r >> 15) * 512 + (r & 511)) * 64 + ((r >> 9) & 63)];
  }
  for (int i = tid; i < 2176; i += 512) { hHi[0][i] = 0; hLo[0][i] = 0; }
  __syncthreads();

  const float ur = ucS[d],       uz = ucS[128 + d],       un = ucS[256 + d];
  const float cr = ucS[384 + d] + bhh[d];
  const float cz = ucS[512 + d] + bhh[128 + d];
  const float cn = ucS[640 + d];
  const float bj2 = bhh[256 + d];

  float hreg[4] = {0.f, 0.f, 0.f, 0.f};
  const int g = d >> 3, e = d & 7;

  for (int t = 0; t < 64; ++t) {
    const int rb = t & 1, wb = rb ^ 1;
    f32x4 acc0 = {0.f, 0.f, 0.f, 0.f};
    f32x4 acc1 = {0.f, 0.f, 0.f, 0.f};
    f32x4 acc2 = {0.f, 0.f, 0.f, 0.f};
#pragma unroll
    for (int c = 0; c < 4; ++c) {
      bf16x8 Ahi = *(const bf16x8*)&hHi[rb][((c * 4 + q) * 17 + s15) * 8];
      bf16x8 Alo = *(const bf16x8*)&hLo[rb][((c * 4 + q) * 17 + s15) * 8];
      acc0 = __builtin_amdgcn_mfma_f32_16x16x32_bf16(Ahi, Bhi[0][c], acc0, 0, 0, 0);
      acc1 = __builtin_amdgcn_mfma_f32_16x16x32_bf16(Ahi, Bhi[1][c], acc1, 0, 0, 0);
      acc2 = __builtin_amdgcn_mfma_f32_16x16x32_bf16(Ahi, Bhi[2][c], acc2, 0, 0, 0);
      acc0 = __builtin_amdgcn_mfma_f32_16x16x32_bf16(Alo, Bhi[0][c], acc0, 0, 0, 0);
      acc1 = __builtin_amdgcn_mfma_f32_16x16x32_bf16(Alo, Bhi[1][c], acc1, 0, 0, 0);
      acc2 = __builtin_amdgcn_mfma_f32_16x16x32_bf16(Alo, Bhi[2][c], acc2, 0, 0, 0);
      acc0 = __builtin_amdgcn_mfma_f32_16x16x32_bf16(Ahi, Blo[0][c], acc0, 0, 0, 0);
      acc1 = __builtin_amdgcn_mfma_f32_16x16x32_bf16(Ahi, Blo[1][c], acc1, 0, 0, 0);
      acc2 = __builtin_amdgcn_mfma_f32_16x16x32_bf16(Ahi, Blo[2][c], acc2, 0, 0, 0);
    }
    float xsv[4];
#pragma unroll
    for (int r = 0; r < 4; ++r) xsv[r] = xsAll[(q * 4 + r) * 65 + t];
#pragma unroll
    for (int r = 0; r < 4; ++r) {
      int s = q * 4 + r;
      float gr = fmaf(xsv[r], ur, cr + acc0[r]);
      float gz = fmaf(xsv[r], uz, cz + acc1[r]);
      float gn = fmaf(xsv[r], un, cn);
      float hn = acc2[r] + bj2;
      float rr = __builtin_amdgcn_rcpf(1.f + __expf(-gr));
      float zz = 1.f - __builtin_amdgcn_rcpf(1.f + __expf(-gz));  // 1-z
      float a = fmaf(rr, hn, gn);
      float ng = 1.f - 2.f * __builtin_amdgcn_rcpf(__expf(2.f * a) + 1.f);
      float hv = fmaf(zz, ng - hreg[r], hreg[r]);
      hreg[r] = hv;
      unsigned int u = __float_as_uint(hv);
      unsigned short hi = (unsigned short)(u >> 16);                 // trunc-hi
      unsigned short lo = bf16_rtn(hv - __uint_as_float(u & 0xFFFF0000u));
      int idx = (g * 17 + s) * 8 + e;
      hHi[wb][idx] = hi;
      hLo[wb][idx] = lo;
    }
    __syncthreads();
  }

#pragma unroll
  for (int r = 0; r < 4; ++r) hFin[(q * 4 + r) * 132 + d] = hreg[r];
  __syncthreads();
  float* h_out = ws + OFF_H;
#pragma unroll
  for (int p = 0; p < 4; ++p) {
    int item = tid + p * 512;
    int s = item >> 7, dd = item & 127;
    h_out[(seq0 + s) * 128 + dd] = hFin[s * 132 + dd];
  }
  for (int s = wave * 2; s < wave * 2 + 2; ++s) {
    float a = hFin[s * 132 + lane] * outW[lane] + hFin[s * 132 + 64 + lane] * outW[64 + lane];
    for (int off = 32; off; off >>= 1) a += __shfl_xor(a, off);
    if (lane == 0) ws[OFF_HV + seq0 + s] = a;
  }
  if (tid < 128) {
    float s = 0.f, q2 = 0.f;
#pragma unroll
    for (int sI = 0; sI < 16; ++sI) {
      float v = hFin[sI * 132 + tid];
      s += v; q2 += v * v;
    }
    ws[OFF_STATS + blockIdx.x * 256 + tid] = s;
    ws[OFF_STATS + blockIdx.x * 256 + 128 + tid] = q2;
  }
}

// ---------------------------------------------------------------------------
// scores via split-bf16 MFMA (R5/R7/R10-verified body), qn LDS-staged.
// 384 blocks; bid%48==0 blocks also compute stats->router->probs.
// ---------------------------------------------------------------------------
__global__ __launch_bounds__(256) void scores_kernel(const float* __restrict__ spaceb,
                                                     const float* __restrict__ routerW,
                                                     const float* __restrict__ routerb,
                                                     float* __restrict__ ws,
                                                     float* __restrict__ d_out) {
  const int bid = blockIdx.x;
  const int chunk = bid & 15, m = (bid >> 4) % 3, b = bid / 48;
  const int n0 = chunk * 32;
  const int tid = threadIdx.x, wave = tid >> 6, lane = tid & 63;
  const int q = lane >> 4, s15 = lane & 15;

  __shared__ __align__(16) unsigned short sHi[16 * 33 * 8];
  __shared__ __align__(16) unsigned short sLo[16 * 33 * 8];
  __shared__ float hsL[32 * 132];
  __shared__ float biasL[128];
  __shared__ float invnL[32];
  __shared__ float qnL[4096];

  const float* hG = ws + OFF_H;
  const unsigned short* SHI = (const unsigned short*)(ws + OFF_SHI);
  const unsigned short* SLO = (const unsigned short*)(ws + OFF_SLO);

  if (tid < 128) biasL[tid] = spaceb[m * 128 + tid];
  {  // stage qn[m] (16 KB)
    const float4* src = (const float4*)(ws + OFF_QN + m * 4096);
    float4* dst = (float4*)qnL;
    for (int i = tid; i < 1024; i += 256) dst[i] = src[i];
  }
  {
    int nn = tid >> 3, kc = tid & 7;
    const float* row = &hG[(b * 512 + n0 + nn) * 128 + kc * 16];
    U8 ph0, pl0, ph1, pl1;
#pragma unroll
    for (int j = 0; j < 8; ++j) {
      float v = row[j];
      unsigned short hi = bf16_rtn(v);
      ph0.s[j] = hi; pl0.s[j] = bf16_rtn(v - bf16_f(hi));
    }
#pragma unroll
    for (int j = 0; j < 8; ++j) {
      float v = row[8 + j];
      unsigned short hi = bf16_rtn(v);
      ph1.s[j] = hi; pl1.s[j] = bf16_rtn(v - bf16_f(hi));
    }
    int g0 = kc * 2;
    *(uint4*)&sHi[(g0 * 33 + nn) * 8] = ph0.u4;
    *(uint4*)&sLo[(g0 * 33 + nn) * 8] = pl0.u4;
    *(uint4*)&sHi[((g0 + 1) * 33 + nn) * 8] = ph1.u4;
    *(uint4*)&sLo[((g0 + 1) * 33 + nn) * 8] = pl1.u4;
  }
  __syncthreads();

  const int nt = wave >> 1;
  const int dt0 = (wave & 1) * 4;
  f32x4 acc[4] = {{0.f,0.f,0.f,0.f},{0.f,0.f,0.f,0.f},{0.f,0.f,0.f,0.f},{0.f,0.f,0.f,0.f}};
#pragma unroll
  for (int c = 0; c < 4; ++c) {
    bf16x8 Ahi = *(const bf16x8*)&sHi[((c * 4 + q) * 33 + nt * 16 + s15) * 8];
    bf16x8 Alo = *(const bf16x8*)&sLo[((c * 4 + q) * 33 + nt * 16 + s15) * 8];
#pragma unroll
    for (int i = 0; i < 4; ++i) {
      int row = m * 16384 + ((dt0 + i) * 16 + s15) * 128 + c * 32 + q * 8;
      bf16x8 Bhi = *(const bf16x8*)&SHI[row];
      bf16x8 Blo = *(const bf16x8*)&SLO[row];
      acc[i] = __builtin_amdgcn_mfma_f32_16x16x32_bf16(Ahi, Bhi, acc[i], 0, 0, 0);
      acc[i] = __builtin_amdgcn_mfma_f32_16x16x32_bf16(Alo, Bhi, acc[i], 0, 0, 0);
      acc[i] = __builtin_amdgcn_mfma_f32_16x16x32_bf16(Ahi, Blo, acc[i], 0, 0, 0);
    }
  }
#pragma unroll
  for (int i = 0; i < 4; ++i) {
    int dcol = (dt0 + i) * 16 + s15;
    float bb = biasL[dcol];
#pragma unroll
    for (int r = 0; r < 4; ++r)
      hsL[(nt * 16 + q * 4 + r) * 132 + dcol] = acc[i][r] + bb;
  }
  __syncthreads();

  {
    int n = tid >> 3, kc = tid & 7;
    float ss = 0.f;
#pragma unroll
    for (int d4 = 0; d4 < 4; ++d4) {
      float4 v = *(const float4*)&hsL[n * 132 + kc * 16 + d4 * 4];
      ss += v.x * v.x + v.y * v.y + v.z * v.z + v.w * v.w;
    }
    ss += __shfl_xor(ss, 1); ss += __shfl_xor(ss, 2); ss += __shfl_xor(ss, 4);
    if (kc == 0) invnL[n] = 1.f / fmaxf(sqrtf(ss), 1e-12f);
  }
  __syncthreads();

  {
    int n = tid & 31, eg = tid >> 5;
    const float* qn = qnL + (eg * 4) * 128;
    float a0 = 0.f, a1 = 0.f, a2 = 0.f, a3 = 0.f;
#pragma unroll
    for (int d4 = 0; d4 < 32; ++d4) {
      float4 hv = *(const float4*)&hsL[n * 132 + d4 * 4];
      float4 q0 = *(const float4*)&qn[d4 * 4];
      float4 q1 = *(const float4*)&qn[128 + d4 * 4];
      float4 q2 = *(const float4*)&qn[256 + d4 * 4];
      float4 q3 = *(const float4*)&qn[384 + d4 * 4];
      a0 += hv.x * q0.x + hv.y * q0.y + hv.z * q0.z + hv.w * q0.w;
      a1 += hv.x * q1.x + hv.y * q1.y + hv.z * q1.z + hv.w * q1.w;
      a2 += hv.x * q2.x + hv.y * q2.y + hv.z * q2.z + hv.w * q2.w;
      a3 += hv.x * q3.x + hv.y * q3.y + hv.z * q3.z + hv.w * q3.w;
    }
    float inv = invnL[n];
    float* sc = ws + OFF_SCORES + ((b * 3 + m) * 32 + eg * 4) * 512 + n0 + n;
    sc[0]    = a0 * inv;
    sc[512]  = a1 * inv;
    sc[1024] = a2 * inv;
    sc[1536] = a3 * inv;
  }

  if ((bid % 48) == 0) {
    __syncthreads();
    float* st = hsL;
    float* lgS = hsL + 256;
    if (tid < 128) {
      float s = 0.f, q2 = 0.f;
      const float* base = ws + OFF_STATS + b * 32 * 256;
      for (int j = 0; j < 32; ++j) {
        s += base[j * 256 + tid];
        q2 += base[j * 256 + 128 + tid];
      }
      float mean = s * (1.f / 512.f);
      float var = (q2 - 512.f * mean * mean) * (1.f / 511.f);  // ddof=1
      st[tid] = mean;
      st[128 + tid] = sqrtf(fmaxf(var, 0.f));
    }
    __syncthreads();
    if (tid < 3) {
      float acc2 = routerb[tid];
      for (int k = 0; k < 256; ++k) acc2 += st[k] * routerW[tid * 256 + k];
      lgS[tid] = acc2;
    }
    __syncthreads();
    if (tid == 0) {
      float mx = fmaxf(lgS[0], fmaxf(lgS[1], lgS[2]));
      float e0 = expf(lgS[0] - mx), e1 = expf(lgS[1] - mx), e2 = expf(lgS[2] - mx);
      float inv = 1.f / (e0 + e1 + e2);
      ws[OFF_PROBS + b * 3 + 0] = e0 * inv;
      ws[OFF_PROBS + b * 3 + 1] = e1 * inv;
      ws[OFF_PROBS + b * 3 + 2] = e2 * inv;
      d_out[4096 + b * 3 + 0] = e0 * inv;
      d_out[4096 + b * 3 + 1] = e1 * inv;
      d_out[4096 + b * 3 + 2] = e2 * inv;
    }
  }
}

// ---------------------------------------------------------------------------
// topk: 192 blocks x 256 (4 wave-rows). Scatters Hmix AND accumulates ev.
// ---------------------------------------------------------------------------
__global__ __launch_bounds__(256) void topk_kernel(float* __restrict__ ws) {
  const int row0 = blockIdx.x * 4;
  const int b = row0 / 96;
  const int tid = threadIdx.x, wave = tid >> 6, lane = tid & 63;
  __shared__ float hvL[512];
  hvL[tid] = ws[OFF_HV + b * 512 + tid];
  hvL[256 + tid] = ws[OFF_HV + b * 512 + 256 + tid];
  __syncthreads();

  int row = row0 + wave;
  int m = (row / 32) % 3, e = row & 31;
  const float* sc = ws + OFF_SCORES + row * 512;
  float prob = ws[OFF_PROBS + b * 3 + m];

  float v[8];
#pragma unroll
  for (int j = 0; j < 8; ++j) v[j] = sc[j * 64 + lane];

  float selv = 0.f; int seli = 0; float maxv = 0.f;
  for (int it = 0; it < 25; ++it) {
    float bv = v[0]; int bj = 0;
#pragma unroll
    for (int j = 1; j < 8; ++j)
      if (v[j] > bv) { bv = v[j]; bj = j; }
    int bidx = bj * 64 + lane;
    for (int off = 32; off; off >>= 1) {
      float ov = __shfl_xor(bv, off);
      int oi = __shfl_xor(bidx, off);
      if (ov > bv || (ov == bv && oi < bidx)) { bv = ov; bidx = oi; }
    }
    if (lane == (bidx & 63)) v[bidx >> 6] = -INFINITY;
    if (it == 0) maxv = bv;
    if (lane == it) { selv = bv; seli = bidx; }
  }
  float ex = (lane < 25) ? __expf((selv - maxv) * (1.f / 0.7f)) : 0.f;
  float den = ex;
  for (int off = 32; off; off >>= 1) den += __shfl_xor(den, off);
  float w = prob * ex / den;
  if (lane < 25)
    atomicAdd(&ws[OFF_HMIX + (b * 32 + e) * 512 + seli], w);
  float evc = (lane < 25) ? w * hvL[seli] : 0.f;
  for (int off = 32; off; off >>= 1) evc += __shfl_xor(evc, off);
  if (lane == 0) atomicAdd(&ws[OFF_EV + b * 32 + e], evc);
}

// ---------------------------------------------------------------------------
// final: 128 blocks (b, 32-n chunk) x 512.
// ---------------------------------------------------------------------------
__global__ __launch_bounds__(512) void final_kernel(const float* __restrict__ prior,
                                                    const float* __restrict__ outb,
                                                    const float* __restrict__ plog,
                                                    float* __restrict__ ws,
                                                    float* __restrict__ d_out) {
  const int bid = blockIdx.x;
  const int b = bid >> 4, ch = bid & 15;
  const int tid = threadIdx.x, wave = tid >> 6, lane = tid & 63;
  __shared__ float hvL[512], evL[32];
  hvL[tid] = ws[OFF_HV + b * 512 + tid];
  if (tid < 32) evL[tid] = ws[OFF_EV + b * 32 + tid];
  __syncthreads();
  float alpha = 1.f / (1.f + expf(-plog[0]));
  float ob = outb[0];
#pragma unroll
  for (int i = 0; i < 4; ++i) {
    int n = ch * 32 + wave * 4 + i;
    const float* pr = prior + n * 512;
    float s1 = 0.f;
#pragma unroll
    for (int j = 0; j < 8; ++j) s1 += pr[j * 64 + lane] * hvL[j * 64 + lane];
    float s2 = 0.f;
    if (lane < 32) s2 = ws[OFF_HMIX + (b * 32 + lane) * 512 + n] * evL[lane];
    float a = alpha * s1 + (1.f - alpha) * s2;
    for (int off = 32; off; off >>= 1) a += __shfl_xor(a, off);
    if (lane == 0) d_out[b * 512 + n] = a + ob;
  }
}

// ---------------------------------------------------------------------------
extern "C" void kernel_launch(void* const* d_in, const int* in_sizes, int n_in,
                              void* d_out, int out_size, void* d_ws, size_t ws_size,
                              hipStream_t stream) {
  const float* x       = (const float*)d_in[0];
  const float* prior   = (const float*)d_in[1];
  const float* projW   = (const float*)d_in[2];
  const float* projb   = (const float*)d_in[3];
  const float* Wih     = (const float*)d_in[4];
  const float* Whh     = (const float*)d_in[5];
  const float* bih     = (const float*)d_in[6];
  const float* bhh     = (const float*)d_in[7];
  const float* spaceW  = (const float*)d_in[8];
  const float* spaceb  = (const float*)d_in[9];
  const float* routerW = (const float*)d_in[10];
  const float* routerb = (const float*)d_in[11];
  const float* outW    = (const float*)d_in[12];
  const float* outb    = (const float*)d_in[13];
  const float* plog    = (const float*)d_in[14];
  const float* queries = (const float*)d_in[15];
  float* ws  = (float*)d_ws;
  float* out = (float*)d_out;

  gru_kernel<<<256, 512, 0, stream>>>(x, Wih, projW, projb, bih, Whh, bhh, outW,
                                      spaceW, queries, ws);
  scores_kernel<<<384, 256, 0, stream>>>(spaceb, routerW, routerb, ws, out);
  topk_kernel<<<192, 256, 0, stream>>>(ws);
  final_kernel<<<128, 512, 0, stream>>>(prior, outb, plog, ws, out);
}

// Round 12
// 192.054 us; speedup vs baseline: 1.1839x; 1.1839x over previous
//
#include <hip/hip_runtime.h>
#include <math.h>

// Problem dims: B=8, N=512, T=64, D=128, E=32, M=3, BN=4096
// ws layout (float offsets)
#define OFF_U      0          // 384
#define OFF_C      384        // 384
#define OFF_QN     768        // 96*128 = 12288
#define OFF_H      13056      // 4096*128
#define OFF_PROBS  537344     // 24
#define OFF_HV     537376     // 4096
#define OFF_SCORES 541472     // 768*512
#define OFF_HMIX   934688     // 8*32*512 = 131072
#define OFF_WHI    1066016    // 24576 floats = 49152 bf16 (Whh hi)
#define OFF_WLO    1090592    // 24576 floats (Whh lo)
#define OFF_SHI    1115168    // 24576 floats (spaceW hi)
#define OFF_SLO    1139744    // 24576 floats (spaceW lo)
#define OFF_STATS  1164320    // 256 blocks * 256 floats
#define OFF_EV     1229856    // 256

typedef short bf16x8 __attribute__((ext_vector_type(8)));
typedef float f32x4 __attribute__((ext_vector_type(4)));

union U8 { unsigned short s[8]; bf16x8 v; uint4 u4; };

__device__ __forceinline__ unsigned short bf16_rtn(float f) {
  unsigned int u = __float_as_uint(f);
  return (unsigned short)((u + 0x7FFFu + ((u >> 16) & 1u)) >> 16);
}
__device__ __forceinline__ float bf16_f(unsigned short h) {
  return __uint_as_float(((unsigned int)h) << 16);
}

// ---------------------------------------------------------------------------
// prep, all-wide (R10-verified): 153 blocks x 256.
// blocks 0..95:   u/c — one wave per row of Wih (coalesced + shuffle reduce)
// blocks 96..119: qn — one wave per query row
// blocks 120..135: Whh bf16 hi/lo split (coalesced)
// blocks 136..151: spaceW bf16 hi/lo split
// block 152: zero ev
// ---------------------------------------------------------------------------
__global__ __launch_bounds__(256) void prep_kernel(const float* __restrict__ Wih,
                                                   const float* __restrict__ projW,
                                                   const float* __restrict__ projb,
                                                   const float* __restrict__ bih,
                                                   const float* __restrict__ queries,
                                                   const float* __restrict__ Whh,
                                                   const float* __restrict__ spaceW,
                                                   float* __restrict__ ws) {
  const int bid = blockIdx.x, tid = threadIdx.x;
  const int wave = tid >> 6, lane = tid & 63;
  if (bid < 96) {
    int r = bid * 4 + wave;  // [0,384)
    float w0 = Wih[r * 128 + lane], w1 = Wih[r * 128 + 64 + lane];
    float u = w0 * projW[lane] + w1 * projW[64 + lane];
    float c = w0 * projb[lane] + w1 * projb[64 + lane];
    for (int off = 32; off; off >>= 1) {
      u += __shfl_xor(u, off);
      c += __shfl_xor(c, off);
    }
    if (lane == 0) {
      ws[OFF_U + r] = u;
      ws[OFF_C + r] = c + bih[r];
    }
  } else if (bid < 120) {
    int r = (bid - 96) * 4 + wave;  // [0,96)
    float v0 = queries[r * 128 + lane], v1 = queries[r * 128 + 64 + lane];
    float ss = v0 * v0 + v1 * v1;
    for (int off = 32; off; off >>= 1) ss += __shfl_xor(ss, off);
    float inv = 1.f / fmaxf(sqrtf(ss), 1e-12f);
    ws[OFF_QN + r * 128 + lane] = v0 * inv;
    ws[OFF_QN + r * 128 + 64 + lane] = v1 * inv;
  } else if (bid < 136) {
    unsigned short* WHI = (unsigned short*)(ws + OFF_WHI);
    unsigned short* WLO = (unsigned short*)(ws + OFF_WLO);
    int base = (bid - 120) * 3072;
    for (int i = tid; i < 3072; i += 256) {
      float w = Whh[base + i];
      unsigned short hi = bf16_rtn(w);
      WHI[base + i] = hi;
      WLO[base + i] = bf16_rtn(w - bf16_f(hi));
    }
  } else if (bid < 152) {
    unsigned short* SHI = (unsigned short*)(ws + OFF_SHI);
    unsigned short* SLO = (unsigned short*)(ws + OFF_SLO);
    int base = (bid - 136) * 3072;
    for (int i = tid; i < 3072; i += 256) {
      float w = spaceW[base + i];
      unsigned short hi = bf16_rtn(w);
      SHI[base + i] = hi;
      SLO[base + i] = bf16_rtn(w - bf16_f(hi));
    }
  } else {
    ws[OFF_EV + tid] = 0.f;
  }
}

// ---------------------------------------------------------------------------
// GRU via W-split bf16 MFMA (gh = Whi·h + Wlo·h, h single RTN-bf16 plane).
// 256 blocks x 512 threads, 16 seqs/block. 24 MFMA/wave/step, one h plane
// (double-buffered). Extras: Hmix zero slice + stats partials.
// ---------------------------------------------------------------------------
__global__ __launch_bounds__(512, 2) void gru_kernel(const float* __restrict__ x,
                                                     const float* __restrict__ bhh,
                                                     const float* __restrict__ outW,
                                                     float* __restrict__ ws) {
  __shared__ __align__(16) unsigned short hB[2][16 * 17 * 8];
  __shared__ float xsAll[16 * 65];
  __shared__ float hFin[16 * 132];

  const int tid = threadIdx.x, wave = tid >> 6, lane = tid & 63;
  const int q = lane >> 4, s15 = lane & 15;
  const int d = wave * 16 + s15;
  const unsigned short* WHI = (const unsigned short*)(ws + OFF_WHI);
  const unsigned short* WLO = (const unsigned short*)(ws + OFF_WLO);

  {
    float4 z4 = make_float4(0.f, 0.f, 0.f, 0.f);
    float4* hm4 = (float4*)(ws + OFF_HMIX);
    if (tid < 128) hm4[blockIdx.x * 128 + tid] = z4;
  }

  bf16x8 Bhi[3][4], Blo[3][4];
#pragma unroll
  for (int t = 0; t < 3; ++t) {
    int row = (wave + 8 * t) * 16 + s15;
#pragma unroll
    for (int c = 0; c < 4; ++c) {
      Bhi[t][c] = *(const bf16x8*)&WHI[row * 128 + c * 32 + q * 8];
      Blo[t][c] = *(const bf16x8*)&WLO[row * 128 + c * 32 + q * 8];
    }
  }
  const float ur = ws[OFF_U + d],       uz = ws[OFF_U + 128 + d], un = ws[OFF_U + 256 + d];
  const float cr = ws[OFF_C + d] + bhh[d];
  const float cz = ws[OFF_C + 128 + d] + bhh[128 + d];
  const float cn = ws[OFF_C + 256 + d];
  const float bj2 = bhh[256 + d];

  const int seq0 = blockIdx.x * 16;
  for (int i = tid; i < 1024; i += 512) {
    int s = i >> 6, tt = i & 63;
    int r = (seq0 + s) * 64 + tt;
    xsAll[s * 65 + tt] = x[((r >> 15) * 512 + (r & 511)) * 64 + ((r >> 9) & 63)];
  }
  for (int i = tid; i < 2176; i += 512) hB[0][i] = 0;
  __syncthreads();

  float hreg[4] = {0.f, 0.f, 0.f, 0.f};
  const int g = d >> 3, e = d & 7;

  for (int t = 0; t < 64; ++t) {
    const int rb = t & 1, wb = rb ^ 1;
    f32x4 acc0 = {0.f, 0.f, 0.f, 0.f};
    f32x4 acc1 = {0.f, 0.f, 0.f, 0.f};
    f32x4 acc2 = {0.f, 0.f, 0.f, 0.f};
#pragma unroll
    for (int c = 0; c < 4; ++c) {
      bf16x8 A = *(const bf16x8*)&hB[rb][((c * 4 + q) * 17 + s15) * 8];
      acc0 = __builtin_amdgcn_mfma_f32_16x16x32_bf16(A, Bhi[0][c], acc0, 0, 0, 0);
      acc1 = __builtin_amdgcn_mfma_f32_16x16x32_bf16(A, Bhi[1][c], acc1, 0, 0, 0);
      acc2 = __builtin_amdgcn_mfma_f32_16x16x32_bf16(A, Bhi[2][c], acc2, 0, 0, 0);
      acc0 = __builtin_amdgcn_mfma_f32_16x16x32_bf16(A, Blo[0][c], acc0, 0, 0, 0);
      acc1 = __builtin_amdgcn_mfma_f32_16x16x32_bf16(A, Blo[1][c], acc1, 0, 0, 0);
      acc2 = __builtin_amdgcn_mfma_f32_16x16x32_bf16(A, Blo[2][c], acc2, 0, 0, 0);
    }
    float xsv[4];
#pragma unroll
    for (int r = 0; r < 4; ++r) xsv[r] = xsAll[(q * 4 + r) * 65 + t];
#pragma unroll
    for (int r = 0; r < 4; ++r) {
      int s = q * 4 + r;
      float gr = fmaf(xsv[r], ur, cr + acc0[r]);
      float gz = fmaf(xsv[r], uz, cz + acc1[r]);
      float gn = fmaf(xsv[r], un, cn);
      float hn = acc2[r] + bj2;
      float rr = __builtin_amdgcn_rcpf(1.f + __expf(-gr));
      float zz = 1.f - __builtin_amdgcn_rcpf(1.f + __expf(-gz));  // 1-z
      float a = fmaf(rr, hn, gn);
      float ng = 1.f - 2.f * __builtin_amdgcn_rcpf(__expf(2.f * a) + 1.f);
      float hv = fmaf(zz, ng - hreg[r], hreg[r]);
      hreg[r] = hv;
      hB[wb][(g * 17 + s) * 8 + e] = bf16_rtn(hv);
    }
    __syncthreads();
  }

#pragma unroll
  for (int r = 0; r < 4; ++r) hFin[(q * 4 + r) * 132 + d] = hreg[r];
  __syncthreads();
  float* h_out = ws + OFF_H;
#pragma unroll
  for (int p = 0; p < 4; ++p) {
    int item = tid + p * 512;
    int s = item >> 7, dd = item & 127;
    h_out[(seq0 + s) * 128 + dd] = hFin[s * 132 + dd];
  }
  for (int s = wave * 2; s < wave * 2 + 2; ++s) {
    float a = hFin[s * 132 + lane] * outW[lane] + hFin[s * 132 + 64 + lane] * outW[64 + lane];
    for (int off = 32; off; off >>= 1) a += __shfl_xor(a, off);
    if (lane == 0) ws[OFF_HV + seq0 + s] = a;
  }
  if (tid < 128) {
    float s = 0.f, q2 = 0.f;
#pragma unroll
    for (int sI = 0; sI < 16; ++sI) {
      float v = hFin[sI * 132 + tid];
      s += v; q2 += v * v;
    }
    ws[OFF_STATS + blockIdx.x * 256 + tid] = s;
    ws[OFF_STATS + blockIdx.x * 256 + 128 + tid] = q2;
  }
}

// ---------------------------------------------------------------------------
// scores via split-bf16 MFMA (R5/R7/R10-verified body). 384 blocks.
// Blocks with bid%48==0 additionally compute stats->router->probs for b.
// ---------------------------------------------------------------------------
__global__ __launch_bounds__(256) void scores_kernel(const float* __restrict__ spaceb,
                                                     const float* __restrict__ routerW,
                                                     const float* __restrict__ routerb,
                                                     float* __restrict__ ws,
                                                     float* __restrict__ d_out) {
  const int bid = blockIdx.x;
  const int chunk = bid & 15, m = (bid >> 4) % 3, b = bid / 48;
  const int n0 = chunk * 32;
  const int tid = threadIdx.x, wave = tid >> 6, lane = tid & 63;
  const int q = lane >> 4, s15 = lane & 15;

  __shared__ __align__(16) unsigned short sHi[16 * 33 * 8];
  __shared__ __align__(16) unsigned short sLo[16 * 33 * 8];
  __shared__ float hsL[32 * 132];
  __shared__ float biasL[128];
  __shared__ float invnL[32];

  const float* hG = ws + OFF_H;
  const unsigned short* SHI = (const unsigned short*)(ws + OFF_SHI);
  const unsigned short* SLO = (const unsigned short*)(ws + OFF_SLO);

  if (tid < 128) biasL[tid] = spaceb[m * 128 + tid];
  {
    int nn = tid >> 3, kc = tid & 7;
    const float* row = &hG[(b * 512 + n0 + nn) * 128 + kc * 16];
    U8 ph0, pl0, ph1, pl1;
#pragma unroll
    for (int j = 0; j < 8; ++j) {
      float v = row[j];
      unsigned short hi = bf16_rtn(v);
      ph0.s[j] = hi; pl0.s[j] = bf16_rtn(v - bf16_f(hi));
    }
#pragma unroll
    for (int j = 0; j < 8; ++j) {
      float v = row[8 + j];
      unsigned short hi = bf16_rtn(v);
      ph1.s[j] = hi; pl1.s[j] = bf16_rtn(v - bf16_f(hi));
    }
    int g0 = kc * 2;
    *(uint4*)&sHi[(g0 * 33 + nn) * 8] = ph0.u4;
    *(uint4*)&sLo[(g0 * 33 + nn) * 8] = pl0.u4;
    *(uint4*)&sHi[((g0 + 1) * 33 + nn) * 8] = ph1.u4;
    *(uint4*)&sLo[((g0 + 1) * 33 + nn) * 8] = pl1.u4;
  }
  __syncthreads();

  const int nt = wave >> 1;
  const int dt0 = (wave & 1) * 4;
  f32x4 acc[4] = {{0.f,0.f,0.f,0.f},{0.f,0.f,0.f,0.f},{0.f,0.f,0.f,0.f},{0.f,0.f,0.f,0.f}};
#pragma unroll
  for (int c = 0; c < 4; ++c) {
    bf16x8 Ahi = *(const bf16x8*)&sHi[((c * 4 + q) * 33 + nt * 16 + s15) * 8];
    bf16x8 Alo = *(const bf16x8*)&sLo[((c * 4 + q) * 33 + nt * 16 + s15) * 8];
#pragma unroll
    for (int i = 0; i < 4; ++i) {
      int row = m * 16384 + ((dt0 + i) * 16 + s15) * 128 + c * 32 + q * 8;
      bf16x8 Bhi = *(const bf16x8*)&SHI[row];
      bf16x8 Blo = *(const bf16x8*)&SLO[row];
      acc[i] = __builtin_amdgcn_mfma_f32_16x16x32_bf16(Ahi, Bhi, acc[i], 0, 0, 0);
      acc[i] = __builtin_amdgcn_mfma_f32_16x16x32_bf16(Alo, Bhi, acc[i], 0, 0, 0);
      acc[i] = __builtin_amdgcn_mfma_f32_16x16x32_bf16(Ahi, Blo, acc[i], 0, 0, 0);
    }
  }
#pragma unroll
  for (int i = 0; i < 4; ++i) {
    int dcol = (dt0 + i) * 16 + s15;
    float bb = biasL[dcol];
#pragma unroll
    for (int r = 0; r < 4; ++r)
      hsL[(nt * 16 + q * 4 + r) * 132 + dcol] = acc[i][r] + bb;
  }
  __syncthreads();

  {
    int n = tid >> 3, kc = tid & 7;
    float ss = 0.f;
#pragma unroll
    for (int d4 = 0; d4 < 4; ++d4) {
      float4 v = *(const float4*)&hsL[n * 132 + kc * 16 + d4 * 4];
      ss += v.x * v.x + v.y * v.y + v.z * v.z + v.w * v.w;
    }
    ss += __shfl_xor(ss, 1); ss += __shfl_xor(ss, 2); ss += __shfl_xor(ss, 4);
    if (kc == 0) invnL[n] = 1.f / fmaxf(sqrtf(ss), 1e-12f);
  }
  __syncthreads();

  {
    int n = tid & 31, eg = tid >> 5;
    const float* qn = ws + OFF_QN + (m * 32 + eg * 4) * 128;
    float a0 = 0.f, a1 = 0.f, a2 = 0.f, a3 = 0.f;
#pragma unroll
    for (int d4 = 0; d4 < 32; ++d4) {
      float4 hv = *(const float4*)&hsL[n * 132 + d4 * 4];
      float4 q0 = *(const float4*)&qn[d4 * 4];
      float4 q1 = *(const float4*)&qn[128 + d4 * 4];
      float4 q2 = *(const float4*)&qn[256 + d4 * 4];
      float4 q3 = *(const float4*)&qn[384 + d4 * 4];
      a0 += hv.x * q0.x + hv.y * q0.y + hv.z * q0.z + hv.w * q0.w;
      a1 += hv.x * q1.x + hv.y * q1.y + hv.z * q1.z + hv.w * q1.w;
      a2 += hv.x * q2.x + hv.y * q2.y + hv.z * q2.z + hv.w * q2.w;
      a3 += hv.x * q3.x + hv.y * q3.y + hv.z * q3.z + hv.w * q3.w;
    }
    float inv = invnL[n];
    float* sc = ws + OFF_SCORES + ((b * 3 + m) * 32 + eg * 4) * 512 + n0 + n;
    sc[0]    = a0 * inv;
    sc[512]  = a1 * inv;
    sc[1024] = a2 * inv;
    sc[1536] = a3 * inv;
  }

  // probs for this b (only 8 blocks do this)
  if ((bid % 48) == 0) {
    __syncthreads();
    float* st = hsL;         // reuse
    float* lgS = hsL + 256;
    if (tid < 128) {
      float s = 0.f, q2 = 0.f;
      const float* base = ws + OFF_STATS + b * 32 * 256;
      for (int j = 0; j < 32; ++j) {
        s += base[j * 256 + tid];
        q2 += base[j * 256 + 128 + tid];
      }
      float mean = s * (1.f / 512.f);
      float var = (q2 - 512.f * mean * mean) * (1.f / 511.f);  // ddof=1
      st[tid] = mean;
      st[128 + tid] = sqrtf(fmaxf(var, 0.f));
    }
    __syncthreads();
    if (tid < 3) {
      float acc2 = routerb[tid];
      for (int k = 0; k < 256; ++k) acc2 += st[k] * routerW[tid * 256 + k];
      lgS[tid] = acc2;
    }
    __syncthreads();
    if (tid == 0) {
      float mx = fmaxf(lgS[0], fmaxf(lgS[1], lgS[2]));
      float e0 = expf(lgS[0] - mx), e1 = expf(lgS[1] - mx), e2 = expf(lgS[2] - mx);
      float inv = 1.f / (e0 + e1 + e2);
      ws[OFF_PROBS + b * 3 + 0] = e0 * inv;
      ws[OFF_PROBS + b * 3 + 1] = e1 * inv;
      ws[OFF_PROBS + b * 3 + 2] = e2 * inv;
      d_out[4096 + b * 3 + 0] = e0 * inv;
      d_out[4096 + b * 3 + 1] = e1 * inv;
      d_out[4096 + b * 3 + 2] = e2 * inv;
    }
  }
}

// ---------------------------------------------------------------------------
// topk: 192 blocks x 256 (4 wave-rows). Scatters Hmix AND accumulates
// ev[b,e] += sum_k w_k * hv[n_k] via one atomic per row.
// ---------------------------------------------------------------------------
__global__ __launch_bounds__(256) void topk_kernel(float* __restrict__ ws) {
  const int row0 = blockIdx.x * 4;
  const int b = row0 / 96;
  const int tid = threadIdx.x, wave = tid >> 6, lane = tid & 63;
  __shared__ float hvL[512];
  hvL[tid] = ws[OFF_HV + b * 512 + tid];
  hvL[256 + tid] = ws[OFF_HV + b * 512 + 256 + tid];
  __syncthreads();

  int row = row0 + wave;
  int m = (row / 32) % 3, e = row & 31;
  const float* sc = ws + OFF_SCORES + row * 512;
  float prob = ws[OFF_PROBS + b * 3 + m];

  float v[8];
#pragma unroll
  for (int j = 0; j < 8; ++j) v[j] = sc[j * 64 + lane];

  float selv = 0.f; int seli = 0; float maxv = 0.f;
  for (int it = 0; it < 25; ++it) {
    float bv = v[0]; int bj = 0;
#pragma unroll
    for (int j = 1; j < 8; ++j)
      if (v[j] > bv) { bv = v[j]; bj = j; }
    int bidx = bj * 64 + lane;
    for (int off = 32; off; off >>= 1) {
      float ov = __shfl_xor(bv, off);
      int oi = __shfl_xor(bidx, off);
      if (ov > bv || (ov == bv && oi < bidx)) { bv = ov; bidx = oi; }
    }
    if (lane == (bidx & 63)) v[bidx >> 6] = -INFINITY;
    if (it == 0) maxv = bv;
    if (lane == it) { selv = bv; seli = bidx; }
  }
  float ex = (lane < 25) ? __expf((selv - maxv) * (1.f / 0.7f)) : 0.f;
  float den = ex;
  for (int off = 32; off; off >>= 1) den += __shfl_xor(den, off);
  float w = prob * ex / den;  // 0 for lanes >= 25
  if (lane < 25)
    atomicAdd(&ws[OFF_HMIX + (b * 32 + e) * 512 + seli], w);
  float evc = (lane < 25) ? w * hvL[seli] : 0.f;
  for (int off = 32; off; off >>= 1) evc += __shfl_xor(evc, off);
  if (lane == 0) atomicAdd(&ws[OFF_EV + b * 32 + e], evc);
}

// ---------------------------------------------------------------------------
// final: 128 blocks (b, 32-n chunk) x 512.
// out[b,n] = alpha*(prior@hv)[n] + (1-alpha)*sum_e Hmix[b,e,n]*ev[b,e] + out_b
// ---------------------------------------------------------------------------
__global__ __launch_bounds__(512) void final_kernel(const float* __restrict__ prior,
                                                    const float* __restrict__ outb,
                                                    const float* __restrict__ plog,
                                                    float* __restrict__ ws,
                                                    float* __restrict__ d_out) {
  const int bid = blockIdx.x;
  const int b = bid >> 4, ch = bid & 15;
  const int tid = threadIdx.x, wave = tid >> 6, lane = tid & 63;
  __shared__ float hvL[512], evL[32];
  hvL[tid] = ws[OFF_HV + b * 512 + tid];
  if (tid < 32) evL[tid] = ws[OFF_EV + b * 32 + tid];
  __syncthreads();
  float alpha = 1.f / (1.f + expf(-plog[0]));
  float ob = outb[0];
#pragma unroll
  for (int i = 0; i < 4; ++i) {
    int n = ch * 32 + wave * 4 + i;
    const float* pr = prior + n * 512;
    float s1 = 0.f;
#pragma unroll
    for (int j = 0; j < 8; ++j) s1 += pr[j * 64 + lane] * hvL[j * 64 + lane];
    float s2 = 0.f;
    if (lane < 32) s2 = ws[OFF_HMIX + (b * 32 + lane) * 512 + n] * evL[lane];
    float a = alpha * s1 + (1.f - alpha) * s2;
    for (int off = 32; off; off >>= 1) a += __shfl_xor(a, off);
    if (lane == 0) d_out[b * 512 + n] = a + ob;
  }
}

// ---------------------------------------------------------------------------
extern "C" void kernel_launch(void* const* d_in, const int* in_sizes, int n_in,
                              void* d_out, int out_size, void* d_ws, size_t ws_size,
                              hipStream_t stream) {
  const float* x       = (const float*)d_in[0];
  const float* prior   = (const float*)d_in[1];
  const float* projW   = (const float*)d_in[2];
  const float* projb   = (const float*)d_in[3];
  const float* Wih     = (const float*)d_in[4];
  const float* Whh     = (const float*)d_in[5];
  const float* bih     = (const float*)d_in[6];
  const float* bhh     = (const float*)d_in[7];
  const float* spaceW  = (const float*)d_in[8];
  const float* spaceb  = (const float*)d_in[9];
  const float* routerW = (const float*)d_in[10];
  const float* routerb = (const float*)d_in[11];
  const float* outW    = (const float*)d_in[12];
  const float* outb    = (const float*)d_in[13];
  const float* plog    = (const float*)d_in[14];
  const float* queries = (const float*)d_in[15];
  float* ws  = (float*)d_ws;
  float* out = (float*)d_out;

  prep_kernel<<<153, 256, 0, stream>>>(Wih, projW, projb, bih, queries, Whh, spaceW, ws);
  gru_kernel<<<256, 512, 0, stream>>>(x, bhh, outW, ws);
  scores_kernel<<<384, 256, 0, stream>>>(spaceb, routerW, routerb, ws, out);
  topk_kernel<<<192, 256, 0, stream>>>(ws);
  final_kernel<<<128, 512, 0, stream>>>(prior, outb, plog, ws, out);
}

// Round 13
// 186.023 us; speedup vs baseline: 1.2223x; 1.0324x over previous
//
#include <hip/hip_runtime.h>
#include <math.h>

// Problem dims: B=8, N=512, T=64, D=128, E=32, M=3, BN=4096
// ws layout (float offsets)
#define OFF_U      0          // 384
#define OFF_C      384        // 384
#define OFF_QWHI   768        // 6144 floats = 12288 bf16 (qn@spaceW hi)
#define OFF_QWLO   6912       // 6144 floats (lo)
#define OFF_H      13056      // 4096*128
#define OFF_PROBS  537344     // 24
#define OFF_HV     537376     // 4096
#define OFF_SCORES 541472     // 768*512
#define OFF_HMIX   934688     // 8*32*512 = 131072
#define OFF_WHI    1066016    // 24576 floats = 49152 bf16 (Whh hi)
#define OFF_WLO    1090592    // 24576 floats (Whh lo)
#define OFF_SHI    1115168    // 24576 floats (spaceW hi)
#define OFF_SLO    1139744    // 24576 floats (spaceW lo)
#define OFF_STATS  1164320    // 256 blocks * 256 floats
#define OFF_EV     1229856    // 256
#define OFF_QB     1230112    // 96 (qn . spaceb)

typedef short bf16x8 __attribute__((ext_vector_type(8)));
typedef float f32x4 __attribute__((ext_vector_type(4)));

union U8 { unsigned short s[8]; bf16x8 v; uint4 u4; };

__device__ __forceinline__ unsigned short bf16_rtn(float f) {
  unsigned int u = __float_as_uint(f);
  return (unsigned short)((u + 0x7FFFu + ((u >> 16) & 1u)) >> 16);
}
__device__ __forceinline__ float bf16_f(unsigned short h) {
  return __uint_as_float(((unsigned int)h) << 16);
}

// ---------------------------------------------------------------------------
// prep, all-wide: 225 blocks x 256.
// 0..95:    u/c — one wave per row of Wih
// 96..111:  Whh bf16 hi/lo split
// 112..127: spaceW bf16 hi/lo split
// 128..223: QW[m,e,:] = qn[m,e]@spaceW[m] (hi/lo) + qb[m,e]
// 224:      zero ev
// ---------------------------------------------------------------------------
__global__ __launch_bounds__(256) void prep_kernel(const float* __restrict__ Wih,
                                                   const float* __restrict__ projW,
                                                   const float* __restrict__ projb,
                                                   const float* __restrict__ bih,
                                                   const float* __restrict__ queries,
                                                   const float* __restrict__ Whh,
                                                   const float* __restrict__ spaceW,
                                                   const float* __restrict__ spaceb,
                                                   float* __restrict__ ws) {
  const int bid = blockIdx.x, tid = threadIdx.x;
  const int wave = tid >> 6, lane = tid & 63;
  if (bid < 96) {
    int r = bid * 4 + wave;  // [0,384)
    float w0 = Wih[r * 128 + lane], w1 = Wih[r * 128 + 64 + lane];
    float u = w0 * projW[lane] + w1 * projW[64 + lane];
    float c = w0 * projb[lane] + w1 * projb[64 + lane];
    for (int off = 32; off; off >>= 1) {
      u += __shfl_xor(u, off);
      c += __shfl_xor(c, off);
    }
    if (lane == 0) {
      ws[OFF_U + r] = u;
      ws[OFF_C + r] = c + bih[r];
    }
  } else if (bid < 112) {
    unsigned short* WHI = (unsigned short*)(ws + OFF_WHI);
    unsigned short* WLO = (unsigned short*)(ws + OFF_WLO);
    int base = (bid - 96) * 3072;
    for (int i = tid; i < 3072; i += 256) {
      float w = Whh[base + i];
      unsigned short hi = bf16_rtn(w);
      WHI[base + i] = hi;
      WLO[base + i] = bf16_rtn(w - bf16_f(hi));
    }
  } else if (bid < 128) {
    unsigned short* SHI = (unsigned short*)(ws + OFF_SHI);
    unsigned short* SLO = (unsigned short*)(ws + OFF_SLO);
    int base = (bid - 112) * 3072;
    for (int i = tid; i < 3072; i += 256) {
      float w = spaceW[base + i];
      unsigned short hi = bf16_rtn(w);
      SHI[base + i] = hi;
      SLO[base + i] = bf16_rtn(w - bf16_f(hi));
    }
  } else if (bid < 224) {
    int qi = bid - 128;  // 0..95
    int m = qi >> 5, e = qi & 31;
    __shared__ float invS, qdS;
    const float* qrow = queries + (m * 32 + e) * 128;
    if (wave == 0) {
      float v0 = qrow[lane], v1 = qrow[64 + lane];
      float ss = v0 * v0 + v1 * v1;
      for (int off = 32; off; off >>= 1) ss += __shfl_xor(ss, off);
      if (lane == 0) invS = 1.f / fmaxf(sqrtf(ss), 1e-12f);
    } else if (wave == 1) {
      float v = qrow[lane] * spaceb[m * 128 + lane] +
                qrow[64 + lane] * spaceb[m * 128 + 64 + lane];
      for (int off = 32; off; off >>= 1) v += __shfl_xor(v, off);
      if (lane == 0) qdS = v;
    }
    __syncthreads();
    if (tid < 128) {
      int din = tid;
      float acc = 0.f;
      for (int dout = 0; dout < 128; ++dout)
        acc += qrow[dout] * spaceW[m * 16384 + dout * 128 + din];
      acc *= invS;
      unsigned short hi = bf16_rtn(acc);
      ((unsigned short*)(ws + OFF_QWHI))[(m * 32 + e) * 128 + din] = hi;
      ((unsigned short*)(ws + OFF_QWLO))[(m * 32 + e) * 128 + din] =
          bf16_rtn(acc - bf16_f(hi));
    }
    if (tid == 255) ws[OFF_QB + m * 32 + e] = qdS * invS;
  } else {
    ws[OFF_EV + tid] = 0.f;
  }
}

// ---------------------------------------------------------------------------
// GRU via W-split bf16 MFMA (R12-verified, 70.2 us). 256 blocks x 512.
// ---------------------------------------------------------------------------
__global__ __launch_bounds__(512, 2) void gru_kernel(const float* __restrict__ x,
                                                     const float* __restrict__ bhh,
                                                     const float* __restrict__ outW,
                                                     float* __restrict__ ws) {
  __shared__ __align__(16) unsigned short hB[2][16 * 17 * 8];
  __shared__ float xsAll[16 * 65];
  __shared__ float hFin[16 * 132];

  const int tid = threadIdx.x, wave = tid >> 6, lane = tid & 63;
  const int q = lane >> 4, s15 = lane & 15;
  const int d = wave * 16 + s15;
  const unsigned short* WHI = (const unsigned short*)(ws + OFF_WHI);
  const unsigned short* WLO = (const unsigned short*)(ws + OFF_WLO);

  {
    float4 z4 = make_float4(0.f, 0.f, 0.f, 0.f);
    float4* hm4 = (float4*)(ws + OFF_HMIX);
    if (tid < 128) hm4[blockIdx.x * 128 + tid] = z4;
  }

  bf16x8 Bhi[3][4], Blo[3][4];
#pragma unroll
  for (int t = 0; t < 3; ++t) {
    int row = (wave + 8 * t) * 16 + s15;
#pragma unroll
    for (int c = 0; c < 4; ++c) {
      Bhi[t][c] = *(const bf16x8*)&WHI[row * 128 + c * 32 + q * 8];
      Blo[t][c] = *(const bf16x8*)&WLO[row * 128 + c * 32 + q * 8];
    }
  }
  const float ur = ws[OFF_U + d],       uz = ws[OFF_U + 128 + d], un = ws[OFF_U + 256 + d];
  const float cr = ws[OFF_C + d] + bhh[d];
  const float cz = ws[OFF_C + 128 + d] + bhh[128 + d];
  const float cn = ws[OFF_C + 256 + d];
  const float bj2 = bhh[256 + d];

  const int seq0 = blockIdx.x * 16;
  for (int i = tid; i < 1024; i += 512) {
    int s = i >> 6, tt = i & 63;
    int r = (seq0 + s) * 64 + tt;
    xsAll[s * 65 + tt] = x[((r >> 15) * 512 + (r & 511)) * 64 + ((r >> 9) & 63)];
  }
  for (int i = tid; i < 2176; i += 512) hB[0][i] = 0;
  __syncthreads();

  float hreg[4] = {0.f, 0.f, 0.f, 0.f};
  const int g = d >> 3, e = d & 7;

  for (int t = 0; t < 64; ++t) {
    const int rb = t & 1, wb = rb ^ 1;
    f32x4 acc0 = {0.f, 0.f, 0.f, 0.f};
    f32x4 acc1 = {0.f, 0.f, 0.f, 0.f};
    f32x4 acc2 = {0.f, 0.f, 0.f, 0.f};
#pragma unroll
    for (int c = 0; c < 4; ++c) {
      bf16x8 A = *(const bf16x8*)&hB[rb][((c * 4 + q) * 17 + s15) * 8];
      acc0 = __builtin_amdgcn_mfma_f32_16x16x32_bf16(A, Bhi[0][c], acc0, 0, 0, 0);
      acc1 = __builtin_amdgcn_mfma_f32_16x16x32_bf16(A, Bhi[1][c], acc1, 0, 0, 0);
      acc2 = __builtin_amdgcn_mfma_f32_16x16x32_bf16(A, Bhi[2][c], acc2, 0, 0, 0);
      acc0 = __builtin_amdgcn_mfma_f32_16x16x32_bf16(A, Blo[0][c], acc0, 0, 0, 0);
      acc1 = __builtin_amdgcn_mfma_f32_16x16x32_bf16(A, Blo[1][c], acc1, 0, 0, 0);
      acc2 = __builtin_amdgcn_mfma_f32_16x16x32_bf16(A, Blo[2][c], acc2, 0, 0, 0);
    }
    float xsv[4];
#pragma unroll
    for (int r = 0; r < 4; ++r) xsv[r] = xsAll[(q * 4 + r) * 65 + t];
#pragma unroll
    for (int r = 0; r < 4; ++r) {
      int s = q * 4 + r;
      float gr = fmaf(xsv[r], ur, cr + acc0[r]);
      float gz = fmaf(xsv[r], uz, cz + acc1[r]);
      float gn = fmaf(xsv[r], un, cn);
      float hn = acc2[r] + bj2;
      float rr = __builtin_amdgcn_rcpf(1.f + __expf(-gr));
      float zz = 1.f - __builtin_amdgcn_rcpf(1.f + __expf(-gz));  // 1-z
      float a = fmaf(rr, hn, gn);
      float ng = 1.f - 2.f * __builtin_amdgcn_rcpf(__expf(2.f * a) + 1.f);
      float hv = fmaf(zz, ng - hreg[r], hreg[r]);
      hreg[r] = hv;
      hB[wb][(g * 17 + s) * 8 + e] = bf16_rtn(hv);
    }
    __syncthreads();
  }

#pragma unroll
  for (int r = 0; r < 4; ++r) hFin[(q * 4 + r) * 132 + d] = hreg[r];
  __syncthreads();
  float* h_out = ws + OFF_H;
#pragma unroll
  for (int p = 0; p < 4; ++p) {
    int item = tid + p * 512;
    int s = item >> 7, dd = item & 127;
    h_out[(seq0 + s) * 128 + dd] = hFin[s * 132 + dd];
  }
  for (int s = wave * 2; s < wave * 2 + 2; ++s) {
    float a = hFin[s * 132 + lane] * outW[lane] + hFin[s * 132 + 64 + lane] * outW[64 + lane];
    for (int off = 32; off; off >>= 1) a += __shfl_xor(a, off);
    if (lane == 0) ws[OFF_HV + seq0 + s] = a;
  }
  if (tid < 128) {
    float s = 0.f, q2 = 0.f;
#pragma unroll
    for (int sI = 0; sI < 16; ++sI) {
      float v = hFin[sI * 132 + tid];
      s += v; q2 += v * v;
    }
    ws[OFF_STATS + blockIdx.x * 256 + tid] = s;
    ws[OFF_STATS + blockIdx.x * 256 + 128 + tid] = q2;
  }
}

// ---------------------------------------------------------------------------
// scores: hs (norm) + score MFMA fused, no dot phase. 384 blocks x 256 (4 waves).
// Wave (nt = wave>>1, half = wave&1): hs d-tiles {half*4..half*4+3} plus
// sc e-tile {half}, all against the same A-fragments.
// Blocks with bid%48==0 additionally compute stats->router->probs for b.
// ---------------------------------------------------------------------------
__global__ __launch_bounds__(256) void scores_kernel(const float* __restrict__ spaceb,
                                                     const float* __restrict__ routerW,
                                                     const float* __restrict__ routerb,
                                                     float* __restrict__ ws,
                                                     float* __restrict__ d_out) {
  const int bid = blockIdx.x;
  const int chunk = bid & 15, m = (bid >> 4) % 3, b = bid / 48;
  const int n0 = chunk * 32;
  const int tid = threadIdx.x, wave = tid >> 6, lane = tid & 63;
  const int q = lane >> 4, s15 = lane & 15;

  __shared__ __align__(16) unsigned short sHi[16 * 33 * 8];
  __shared__ __align__(16) unsigned short sLo[16 * 33 * 8];
  __shared__ float hsL[32 * 132];
  __shared__ float biasL[128];
  __shared__ float invnL[32];
  __shared__ float qbL[32];

  const float* hG = ws + OFF_H;
  const unsigned short* SHI = (const unsigned short*)(ws + OFF_SHI);
  const unsigned short* SLO = (const unsigned short*)(ws + OFF_SLO);
  const unsigned short* QWHI = (const unsigned short*)(ws + OFF_QWHI);
  const unsigned short* QWLO = (const unsigned short*)(ws + OFF_QWLO);

  if (tid < 128) biasL[tid] = spaceb[m * 128 + tid];
  else if (tid < 160) qbL[tid - 128] = ws[OFF_QB + m * 32 + (tid - 128)];
  {
    int nn = tid >> 3, kc = tid & 7;
    const float* row = &hG[(b * 512 + n0 + nn) * 128 + kc * 16];
    U8 ph0, pl0, ph1, pl1;
#pragma unroll
    for (int j = 0; j < 8; ++j) {
      float v = row[j];
      unsigned short hi = bf16_rtn(v);
      ph0.s[j] = hi; pl0.s[j] = bf16_rtn(v - bf16_f(hi));
    }
#pragma unroll
    for (int j = 0; j < 8; ++j) {
      float v = row[8 + j];
      unsigned short hi = bf16_rtn(v);
      ph1.s[j] = hi; pl1.s[j] = bf16_rtn(v - bf16_f(hi));
    }
    int g0 = kc * 2;
    *(uint4*)&sHi[(g0 * 33 + nn) * 8] = ph0.u4;
    *(uint4*)&sLo[(g0 * 33 + nn) * 8] = pl0.u4;
    *(uint4*)&sHi[((g0 + 1) * 33 + nn) * 8] = ph1.u4;
    *(uint4*)&sLo[((g0 + 1) * 33 + nn) * 8] = pl1.u4;
  }
  __syncthreads();

  const int nt = wave >> 1;
  const int half = wave & 1;
  const int dt0 = half * 4;
  f32x4 acc[4] = {{0.f,0.f,0.f,0.f},{0.f,0.f,0.f,0.f},{0.f,0.f,0.f,0.f},{0.f,0.f,0.f,0.f}};
  f32x4 accS = {0.f, 0.f, 0.f, 0.f};
#pragma unroll
  for (int c = 0; c < 4; ++c) {
    bf16x8 Ahi = *(const bf16x8*)&sHi[((c * 4 + q) * 33 + nt * 16 + s15) * 8];
    bf16x8 Alo = *(const bf16x8*)&sLo[((c * 4 + q) * 33 + nt * 16 + s15) * 8];
#pragma unroll
    for (int i = 0; i < 4; ++i) {
      int row = m * 16384 + ((dt0 + i) * 16 + s15) * 128 + c * 32 + q * 8;
      bf16x8 Bhi = *(const bf16x8*)&SHI[row];
      bf16x8 Blo = *(const bf16x8*)&SLO[row];
      acc[i] = __builtin_amdgcn_mfma_f32_16x16x32_bf16(Ahi, Bhi, acc[i], 0, 0, 0);
      acc[i] = __builtin_amdgcn_mfma_f32_16x16x32_bf16(Alo, Bhi, acc[i], 0, 0, 0);
      acc[i] = __builtin_amdgcn_mfma_f32_16x16x32_bf16(Ahi, Blo, acc[i], 0, 0, 0);
    }
    {
      int row = (m * 32 + half * 16 + s15) * 128 + c * 32 + q * 8;
      bf16x8 Qhi = *(const bf16x8*)&QWHI[row];
      bf16x8 Qlo = *(const bf16x8*)&QWLO[row];
      accS = __builtin_amdgcn_mfma_f32_16x16x32_bf16(Ahi, Qhi, accS, 0, 0, 0);
      accS = __builtin_amdgcn_mfma_f32_16x16x32_bf16(Alo, Qhi, accS, 0, 0, 0);
      accS = __builtin_amdgcn_mfma_f32_16x16x32_bf16(Ahi, Qlo, accS, 0, 0, 0);
    }
  }
#pragma unroll
  for (int i = 0; i < 4; ++i) {
    int dcol = (dt0 + i) * 16 + s15;
    float bb = biasL[dcol];
#pragma unroll
    for (int r = 0; r < 4; ++r)
      hsL[(nt * 16 + q * 4 + r) * 132 + dcol] = acc[i][r] + bb;
  }
  __syncthreads();

  {
    int n = tid >> 3, kc = tid & 7;
    float ss = 0.f;
#pragma unroll
    for (int d4 = 0; d4 < 4; ++d4) {
      float4 v = *(const float4*)&hsL[n * 132 + kc * 16 + d4 * 4];
      ss += v.x * v.x + v.y * v.y + v.z * v.z + v.w * v.w;
    }
    ss += __shfl_xor(ss, 1); ss += __shfl_xor(ss, 2); ss += __shfl_xor(ss, 4);
    if (kc == 0) invnL[n] = 1.f / fmaxf(sqrtf(ss), 1e-12f);
  }
  __syncthreads();

  {
    int e = half * 16 + s15;
    float qb = qbL[e];
    int nb = nt * 16 + q * 4;
    float4 o;
    o.x = (accS[0] + qb) * invnL[nb + 0];
    o.y = (accS[1] + qb) * invnL[nb + 1];
    o.z = (accS[2] + qb) * invnL[nb + 2];
    o.w = (accS[3] + qb) * invnL[nb + 3];
    *(float4*)&ws[OFF_SCORES + ((b * 3 + m) * 32 + e) * 512 + n0 + nb] = o;
  }

  // probs for this b (only 8 blocks do this)
  if ((bid % 48) == 0) {
    __syncthreads();
    float* st = hsL;
    float* lgS = hsL + 256;
    if (tid < 128) {
      float s = 0.f, q2 = 0.f;
      const float* base = ws + OFF_STATS + b * 32 * 256;
      for (int j = 0; j < 32; ++j) {
        s += base[j * 256 + tid];
        q2 += base[j * 256 + 128 + tid];
      }
      float mean = s * (1.f / 512.f);
      float var = (q2 - 512.f * mean * mean) * (1.f / 511.f);  // ddof=1
      st[tid] = mean;
      st[128 + tid] = sqrtf(fmaxf(var, 0.f));
    }
    __syncthreads();
    if (tid < 3) {
      float acc2 = routerb[tid];
      for (int k = 0; k < 256; ++k) acc2 += st[k] * routerW[tid * 256 + k];
      lgS[tid] = acc2;
    }
    __syncthreads();
    if (tid == 0) {
      float mx = fmaxf(lgS[0], fmaxf(lgS[1], lgS[2]));
      float e0 = expf(lgS[0] - mx), e1 = expf(lgS[1] - mx), e2 = expf(lgS[2] - mx);
      float inv = 1.f / (e0 + e1 + e2);
      ws[OFF_PROBS + b * 3 + 0] = e0 * inv;
      ws[OFF_PROBS + b * 3 + 1] = e1 * inv;
      ws[OFF_PROBS + b * 3 + 2] = e2 * inv;
      d_out[4096 + b * 3 + 0] = e0 * inv;
      d_out[4096 + b * 3 + 1] = e1 * inv;
      d_out[4096 + b * 3 + 2] = e2 * inv;
    }
  }
}

// ---------------------------------------------------------------------------
// topk: 192 blocks x 256 (4 wave-rows). Scatters Hmix AND accumulates ev.
// ---------------------------------------------------------------------------
__global__ __launch_bounds__(256) void topk_kernel(float* __restrict__ ws) {
  const int row0 = blockIdx.x * 4;
  const int b = row0 / 96;
  const int tid = threadIdx.x, wave = tid >> 6, lane = tid & 63;
  __shared__ float hvL[512];
  hvL[tid] = ws[OFF_HV + b * 512 + tid];
  hvL[256 + tid] = ws[OFF_HV + b * 512 + 256 + tid];
  __syncthreads();

  int row = row0 + wave;
  int m = (row / 32) % 3, e = row & 31;
  const float* sc = ws + OFF_SCORES + row * 512;
  float prob = ws[OFF_PROBS + b * 3 + m];

  float v[8];
#pragma unroll
  for (int j = 0; j < 8; ++j) v[j] = sc[j * 64 + lane];

  float selv = 0.f; int seli = 0; float maxv = 0.f;
  for (int it = 0; it < 25; ++it) {
    float bv = v[0]; int bj = 0;
#pragma unroll
    for (int j = 1; j < 8; ++j)
      if (v[j] > bv) { bv = v[j]; bj = j; }
    int bidx = bj * 64 + lane;
    for (int off = 32; off; off >>= 1) {
      float ov = __shfl_xor(bv, off);
      int oi = __shfl_xor(bidx, off);
      if (ov > bv || (ov == bv && oi < bidx)) { bv = ov; bidx = oi; }
    }
    if (lane == (bidx & 63)) v[bidx >> 6] = -INFINITY;
    if (it == 0) maxv = bv;
    if (lane == it) { selv = bv; seli = bidx; }
  }
  float ex = (lane < 25) ? __expf((selv - maxv) * (1.f / 0.7f)) : 0.f;
  float den = ex;
  for (int off = 32; off; off >>= 1) den += __shfl_xor(den, off);
  float w = prob * ex / den;  // 0 for lanes >= 25
  if (lane < 25)
    atomicAdd(&ws[OFF_HMIX + (b * 32 + e) * 512 + seli], w);
  float evc = (lane < 25) ? w * hvL[seli] : 0.f;
  for (int off = 32; off; off >>= 1) evc += __shfl_xor(evc, off);
  if (lane == 0) atomicAdd(&ws[OFF_EV + b * 32 + e], evc);
}

// ---------------------------------------------------------------------------
// final: 128 blocks (b, 32-n chunk) x 512.
// ---------------------------------------------------------------------------
__global__ __launch_bounds__(512) void final_kernel(const float* __restrict__ prior,
                                                    const float* __restrict__ outb,
                                                    const float* __restrict__ plog,
                                                    float* __restrict__ ws,
                                                    float* __restrict__ d_out) {
  const int bid = blockIdx.x;
  const int b = bid >> 4, ch = bid & 15;
  const int tid = threadIdx.x, wave = tid >> 6, lane = tid & 63;
  __shared__ float hvL[512], evL[32];
  hvL[tid] = ws[OFF_HV + b * 512 + tid];
  if (tid < 32) evL[tid] = ws[OFF_EV + b * 32 + tid];
  __syncthreads();
  float alpha = 1.f / (1.f + expf(-plog[0]));
  float ob = outb[0];
#pragma unroll
  for (int i = 0; i < 4; ++i) {
    int n = ch * 32 + wave * 4 + i;
    const float* pr = prior + n * 512;
    float s1 = 0.f;
#pragma unroll
    for (int j = 0; j < 8; ++j) s1 += pr[j * 64 + lane] * hvL[j * 64 + lane];
    float s2 = 0.f;
    if (lane < 32) s2 = ws[OFF_HMIX + (b * 32 + lane) * 512 + n] * evL[lane];
    float a = alpha * s1 + (1.f - alpha) * s2;
    for (int off = 32; off; off >>= 1) a += __shfl_xor(a, off);
    if (lane == 0) d_out[b * 512 + n] = a + ob;
  }
}

// ---------------------------------------------------------------------------
extern "C" void kernel_launch(void* const* d_in, const int* in_sizes, int n_in,
                              void* d_out, int out_size, void* d_ws, size_t ws_size,
                              hipStream_t stream) {
  const float* x       = (const float*)d_in[0];
  const float* prior   = (const float*)d_in[1];
  const float* projW   = (const float*)d_in[2];
  const float* projb   = (const float*)d_in[3];
  const float* Wih     = (const float*)d_in[4];
  const float* Whh     = (const float*)d_in[5];
  const float* bih     = (const float*)d_in[6];
  const float* bhh     = (const float*)d_in[7];
  const float* spaceW  = (const float*)d_in[8];
  const float* spaceb  = (const float*)d_in[9];
  const float* routerW = (const float*)d_in[10];
  const float* routerb = (const float*)d_in[11];
  const float* outW    = (const float*)d_in[12];
  const float* outb    = (const float*)d_in[13];
  const float* plog    = (const float*)d_in[14];
  const float* queries = (const float*)d_in[15];
  float* ws  = (float*)d_ws;
  float* out = (float*)d_out;

  prep_kernel<<<225, 256, 0, stream>>>(Wih, projW, projb, bih, queries, Whh,
                                       spaceW, spaceb, ws);
  gru_kernel<<<256, 512, 0, stream>>>(x, bhh, outW, ws);
  scores_kernel<<<384, 256, 0, stream>>>(spaceb, routerW, routerb, ws, out);
  topk_kernel<<<192, 256, 0, stream>>>(ws);
  final_kernel<<<128, 512, 0, stream>>>(prior, outb, plog, ws, out);
}

// Round 14
// 174.908 us; speedup vs baseline: 1.2999x; 1.0635x over previous
//
#include <hip/hip_runtime.h>
#include <math.h>

// Problem dims: B=8, N=512, T=64, D=128, E=32, M=3, BN=4096
// ws layout (float offsets)
#define OFF_U      0          // 384
#define OFF_C      384        // 384
#define OFF_QWHI   768        // 6144 floats = 12288 bf16 (qn@spaceW hi)
#define OFF_QWLO   6912       // 6144 floats (lo)
#define OFF_H      13056      // 4096*128
#define OFF_PROBS  537344     // 24
#define OFF_HV     537376     // 4096
#define OFF_SCORES 541472     // 768*512
#define OFF_HMIX   934688     // 8*32*512 = 131072
#define OFF_WHI    1066016    // 24576 floats = 49152 bf16 (Whh bf16)
#define OFF_SHI    1115168    // 24576 floats (spaceW hi)
#define OFF_SLO    1139744    // 24576 floats (spaceW lo)
#define OFF_STATS  1164320    // 256 blocks * 256 floats
#define OFF_EV     1229856    // 256
#define OFF_QB     1230112    // 96 (qn . spaceb)

typedef short bf16x8 __attribute__((ext_vector_type(8)));
typedef float f32x4 __attribute__((ext_vector_type(4)));

union U8 { unsigned short s[8]; bf16x8 v; uint4 u4; };

__device__ __forceinline__ unsigned short bf16_rtn(float f) {
  unsigned int u = __float_as_uint(f);
  return (unsigned short)((u + 0x7FFFu + ((u >> 16) & 1u)) >> 16);
}
__device__ __forceinline__ float bf16_f(unsigned short h) {
  return __uint_as_float(((unsigned int)h) << 16);
}

// ---------------------------------------------------------------------------
// prep, all-wide: 225 blocks x 256.
// 0..95:    u/c — one wave per row of Wih
// 96..111:  Whh bf16 (single plane)
// 112..127: spaceW bf16 hi/lo split
// 128..223: QW[m,e,:] = qn[m,e]@spaceW[m] (hi/lo) + qb[m,e]
// 224:      zero ev
// ---------------------------------------------------------------------------
__global__ __launch_bounds__(256) void prep_kernel(const float* __restrict__ Wih,
                                                   const float* __restrict__ projW,
                                                   const float* __restrict__ projb,
                                                   const float* __restrict__ bih,
                                                   const float* __restrict__ queries,
                                                   const float* __restrict__ Whh,
                                                   const float* __restrict__ spaceW,
                                                   const float* __restrict__ spaceb,
                                                   float* __restrict__ ws) {
  const int bid = blockIdx.x, tid = threadIdx.x;
  const int wave = tid >> 6, lane = tid & 63;
  if (bid < 96) {
    int r = bid * 4 + wave;  // [0,384)
    float w0 = Wih[r * 128 + lane], w1 = Wih[r * 128 + 64 + lane];
    float u = w0 * projW[lane] + w1 * projW[64 + lane];
    float c = w0 * projb[lane] + w1 * projb[64 + lane];
    for (int off = 32; off; off >>= 1) {
      u += __shfl_xor(u, off);
      c += __shfl_xor(c, off);
    }
    if (lane == 0) {
      ws[OFF_U + r] = u;
      ws[OFF_C + r] = c + bih[r];
    }
  } else if (bid < 112) {
    unsigned short* WHI = (unsigned short*)(ws + OFF_WHI);
    int base = (bid - 96) * 3072;
    for (int i = tid; i < 3072; i += 256)
      WHI[base + i] = bf16_rtn(Whh[base + i]);
  } else if (bid < 128) {
    unsigned short* SHI = (unsigned short*)(ws + OFF_SHI);
    unsigned short* SLO = (unsigned short*)(ws + OFF_SLO);
    int base = (bid - 112) * 3072;
    for (int i = tid; i < 3072; i += 256) {
      float w = spaceW[base + i];
      unsigned short hi = bf16_rtn(w);
      SHI[base + i] = hi;
      SLO[base + i] = bf16_rtn(w - bf16_f(hi));
    }
  } else if (bid < 224) {
    int qi = bid - 128;  // 0..95
    int m = qi >> 5, e = qi & 31;
    __shared__ float invS, qdS;
    const float* qrow = queries + (m * 32 + e) * 128;
    if (wave == 0) {
      float v0 = qrow[lane], v1 = qrow[64 + lane];
      float ss = v0 * v0 + v1 * v1;
      for (int off = 32; off; off >>= 1) ss += __shfl_xor(ss, off);
      if (lane == 0) invS = 1.f / fmaxf(sqrtf(ss), 1e-12f);
    } else if (wave == 1) {
      float v = qrow[lane] * spaceb[m * 128 + lane] +
                qrow[64 + lane] * spaceb[m * 128 + 64 + lane];
      for (int off = 32; off; off >>= 1) v += __shfl_xor(v, off);
      if (lane == 0) qdS = v;
    }
    __syncthreads();
    if (tid < 128) {
      int din = tid;
      float acc = 0.f;
      for (int dout = 0; dout < 128; ++dout)
        acc += qrow[dout] * spaceW[m * 16384 + dout * 128 + din];
      acc *= invS;
      unsigned short hi = bf16_rtn(acc);
      ((unsigned short*)(ws + OFF_QWHI))[(m * 32 + e) * 128 + din] = hi;
      ((unsigned short*)(ws + OFF_QWLO))[(m * 32 + e) * 128 + din] =
          bf16_rtn(acc - bf16_f(hi));
    }
    if (tid == 255) ws[OFF_QB + m * 32 + e] = qdS * invS;
  } else {
    ws[OFF_EV + tid] = 0.f;
  }
}

// ---------------------------------------------------------------------------
// GRU via single-plane bf16 MFMA (gh = bf16(W)·bf16(h), fp32 accumulate).
// 256 blocks x 512 threads, 16 seqs/block, 12 MFMA/wave/step.
// Extras: Hmix zero slice + stats partials.
// ---------------------------------------------------------------------------
__global__ __launch_bounds__(512, 2) void gru_kernel(const float* __restrict__ x,
                                                     const float* __restrict__ bhh,
                                                     const float* __restrict__ outW,
                                                     float* __restrict__ ws) {
  __shared__ __align__(16) unsigned short hB[2][16 * 17 * 8];
  __shared__ float xsAll[16 * 65];
  __shared__ float hFin[16 * 132];

  const int tid = threadIdx.x, wave = tid >> 6, lane = tid & 63;
  const int q = lane >> 4, s15 = lane & 15;
  const int d = wave * 16 + s15;
  const unsigned short* WHI = (const unsigned short*)(ws + OFF_WHI);

  {
    float4 z4 = make_float4(0.f, 0.f, 0.f, 0.f);
    float4* hm4 = (float4*)(ws + OFF_HMIX);
    if (tid < 128) hm4[blockIdx.x * 128 + tid] = z4;
  }

  bf16x8 Bh[3][4];
#pragma unroll
  for (int t = 0; t < 3; ++t) {
    int row = (wave + 8 * t) * 16 + s15;
#pragma unroll
    for (int c = 0; c < 4; ++c)
      Bh[t][c] = *(const bf16x8*)&WHI[row * 128 + c * 32 + q * 8];
  }
  const float ur = ws[OFF_U + d],       uz = ws[OFF_U + 128 + d], un = ws[OFF_U + 256 + d];
  const float cr = ws[OFF_C + d] + bhh[d];
  const float cz = ws[OFF_C + 128 + d] + bhh[128 + d];
  const float cn = ws[OFF_C + 256 + d];
  const float bj2 = bhh[256 + d];

  const int seq0 = blockIdx.x * 16;
  for (int i = tid; i < 1024; i += 512) {
    int s = i >> 6, tt = i & 63;
    int r = (seq0 + s) * 64 + tt;
    xsAll[s * 65 + tt] = x[((r >> 15) * 512 + (r & 511)) * 64 + ((r >> 9) & 63)];
  }
  for (int i = tid; i < 2176; i += 512) hB[0][i] = 0;
  __syncthreads();

  float hreg[4] = {0.f, 0.f, 0.f, 0.f};
  const int g = d >> 3, e = d & 7;

  for (int t = 0; t < 64; ++t) {
    const int rb = t & 1, wb = rb ^ 1;
    f32x4 acc0 = {0.f, 0.f, 0.f, 0.f};
    f32x4 acc1 = {0.f, 0.f, 0.f, 0.f};
    f32x4 acc2 = {0.f, 0.f, 0.f, 0.f};
#pragma unroll
    for (int c = 0; c < 4; ++c) {
      bf16x8 A = *(const bf16x8*)&hB[rb][((c * 4 + q) * 17 + s15) * 8];
      acc0 = __builtin_amdgcn_mfma_f32_16x16x32_bf16(A, Bh[0][c], acc0, 0, 0, 0);
      acc1 = __builtin_amdgcn_mfma_f32_16x16x32_bf16(A, Bh[1][c], acc1, 0, 0, 0);
      acc2 = __builtin_amdgcn_mfma_f32_16x16x32_bf16(A, Bh[2][c], acc2, 0, 0, 0);
    }
    float xsv[4];
#pragma unroll
    for (int r = 0; r < 4; ++r) xsv[r] = xsAll[(q * 4 + r) * 65 + t];
#pragma unroll
    for (int r = 0; r < 4; ++r) {
      int s = q * 4 + r;
      float gr = fmaf(xsv[r], ur, cr + acc0[r]);
      float gz = fmaf(xsv[r], uz, cz + acc1[r]);
      float gn = fmaf(xsv[r], un, cn);
      float hn = acc2[r] + bj2;
      float rr = __builtin_amdgcn_rcpf(1.f + __expf(-gr));
      float zm = __builtin_amdgcn_rcpf(1.f + __expf(gz));   // 1 - sigmoid(gz)
      float a = fmaf(rr, hn, gn);
      float ng = 1.f - 2.f * __builtin_amdgcn_rcpf(__expf(2.f * a) + 1.f);
      float hv = fmaf(zm, ng - hreg[r], hreg[r]);           // (1-z)*ng + z*h
      hreg[r] = hv;
      hB[wb][(g * 17 + s) * 8 + e] = bf16_rtn(hv);
    }
    __syncthreads();
  }

#pragma unroll
  for (int r = 0; r < 4; ++r) hFin[(q * 4 + r) * 132 + d] = hreg[r];
  __syncthreads();
  float* h_out = ws + OFF_H;
#pragma unroll
  for (int p = 0; p < 4; ++p) {
    int item = tid + p * 512;
    int s = item >> 7, dd = item & 127;
    h_out[(seq0 + s) * 128 + dd] = hFin[s * 132 + dd];
  }
  for (int s = wave * 2; s < wave * 2 + 2; ++s) {
    float a = hFin[s * 132 + lane] * outW[lane] + hFin[s * 132 + 64 + lane] * outW[64 + lane];
    for (int off = 32; off; off >>= 1) a += __shfl_xor(a, off);
    if (lane == 0) ws[OFF_HV + seq0 + s] = a;
  }
  if (tid < 128) {
    float s = 0.f, q2 = 0.f;
#pragma unroll
    for (int sI = 0; sI < 16; ++sI) {
      float v = hFin[sI * 132 + tid];
      s += v; q2 += v * v;
    }
    ws[OFF_STATS + blockIdx.x * 256 + tid] = s;
    ws[OFF_STATS + blockIdx.x * 256 + 128 + tid] = q2;
  }
}

// ---------------------------------------------------------------------------
// scores: hs (norm) + score MFMA fused (R13-verified). 384 blocks x 256.
// Blocks with bid%48==0 additionally compute stats->router->probs for b.
// ---------------------------------------------------------------------------
__global__ __launch_bounds__(256) void scores_kernel(const float* __restrict__ spaceb,
                                                     const float* __restrict__ routerW,
                                                     const float* __restrict__ routerb,
                                                     float* __restrict__ ws,
                                                     float* __restrict__ d_out) {
  const int bid = blockIdx.x;
  const int chunk = bid & 15, m = (bid >> 4) % 3, b = bid / 48;
  const int n0 = chunk * 32;
  const int tid = threadIdx.x, wave = tid >> 6, lane = tid & 63;
  const int q = lane >> 4, s15 = lane & 15;

  __shared__ __align__(16) unsigned short sHi[16 * 33 * 8];
  __shared__ __align__(16) unsigned short sLo[16 * 33 * 8];
  __shared__ float hsL[32 * 132];
  __shared__ float biasL[128];
  __shared__ float invnL[32];
  __shared__ float qbL[32];

  const float* hG = ws + OFF_H;
  const unsigned short* SHI = (const unsigned short*)(ws + OFF_SHI);
  const unsigned short* SLO = (const unsigned short*)(ws + OFF_SLO);
  const unsigned short* QWHI = (const unsigned short*)(ws + OFF_QWHI);
  const unsigned short* QWLO = (const unsigned short*)(ws + OFF_QWLO);

  if (tid < 128) biasL[tid] = spaceb[m * 128 + tid];
  else if (tid < 160) qbL[tid - 128] = ws[OFF_QB + m * 32 + (tid - 128)];
  {
    int nn = tid >> 3, kc = tid & 7;
    const float* row = &hG[(b * 512 + n0 + nn) * 128 + kc * 16];
    U8 ph0, pl0, ph1, pl1;
#pragma unroll
    for (int j = 0; j < 8; ++j) {
      float v = row[j];
      unsigned short hi = bf16_rtn(v);
      ph0.s[j] = hi; pl0.s[j] = bf16_rtn(v - bf16_f(hi));
    }
#pragma unroll
    for (int j = 0; j < 8; ++j) {
      float v = row[8 + j];
      unsigned short hi = bf16_rtn(v);
      ph1.s[j] = hi; pl1.s[j] = bf16_rtn(v - bf16_f(hi));
    }
    int g0 = kc * 2;
    *(uint4*)&sHi[(g0 * 33 + nn) * 8] = ph0.u4;
    *(uint4*)&sLo[(g0 * 33 + nn) * 8] = pl0.u4;
    *(uint4*)&sHi[((g0 + 1) * 33 + nn) * 8] = ph1.u4;
    *(uint4*)&sLo[((g0 + 1) * 33 + nn) * 8] = pl1.u4;
  }
  __syncthreads();

  const int nt = wave >> 1;
  const int half = wave & 1;
  const int dt0 = half * 4;
  f32x4 acc[4] = {{0.f,0.f,0.f,0.f},{0.f,0.f,0.f,0.f},{0.f,0.f,0.f,0.f},{0.f,0.f,0.f,0.f}};
  f32x4 accS = {0.f, 0.f, 0.f, 0.f};
#pragma unroll
  for (int c = 0; c < 4; ++c) {
    bf16x8 Ahi = *(const bf16x8*)&sHi[((c * 4 + q) * 33 + nt * 16 + s15) * 8];
    bf16x8 Alo = *(const bf16x8*)&sLo[((c * 4 + q) * 33 + nt * 16 + s15) * 8];
#pragma unroll
    for (int i = 0; i < 4; ++i) {
      int row = m * 16384 + ((dt0 + i) * 16 + s15) * 128 + c * 32 + q * 8;
      bf16x8 Bhi = *(const bf16x8*)&SHI[row];
      bf16x8 Blo = *(const bf16x8*)&SLO[row];
      acc[i] = __builtin_amdgcn_mfma_f32_16x16x32_bf16(Ahi, Bhi, acc[i], 0, 0, 0);
      acc[i] = __builtin_amdgcn_mfma_f32_16x16x32_bf16(Alo, Bhi, acc[i], 0, 0, 0);
      acc[i] = __builtin_amdgcn_mfma_f32_16x16x32_bf16(Ahi, Blo, acc[i], 0, 0, 0);
    }
    {
      int row = (m * 32 + half * 16 + s15) * 128 + c * 32 + q * 8;
      bf16x8 Qhi = *(const bf16x8*)&QWHI[row];
      bf16x8 Qlo = *(const bf16x8*)&QWLO[row];
      accS = __builtin_amdgcn_mfma_f32_16x16x32_bf16(Ahi, Qhi, accS, 0, 0, 0);
      accS = __builtin_amdgcn_mfma_f32_16x16x32_bf16(Alo, Qhi, accS, 0, 0, 0);
      accS = __builtin_amdgcn_mfma_f32_16x16x32_bf16(Ahi, Qlo, accS, 0, 0, 0);
    }
  }
#pragma unroll
  for (int i = 0; i < 4; ++i) {
    int dcol = (dt0 + i) * 16 + s15;
    float bb = biasL[dcol];
#pragma unroll
    for (int r = 0; r < 4; ++r)
      hsL[(nt * 16 + q * 4 + r) * 132 + dcol] = acc[i][r] + bb;
  }
  __syncthreads();

  {
    int n = tid >> 3, kc = tid & 7;
    float ss = 0.f;
#pragma unroll
    for (int d4 = 0; d4 < 4; ++d4) {
      float4 v = *(const float4*)&hsL[n * 132 + kc * 16 + d4 * 4];
      ss += v.x * v.x + v.y * v.y + v.z * v.z + v.w * v.w;
    }
    ss += __shfl_xor(ss, 1); ss += __shfl_xor(ss, 2); ss += __shfl_xor(ss, 4);
    if (kc == 0) invnL[n] = 1.f / fmaxf(sqrtf(ss), 1e-12f);
  }
  __syncthreads();

  {
    int e = half * 16 + s15;
    float qb = qbL[e];
    int nb = nt * 16 + q * 4;
    float4 o;
    o.x = (accS[0] + qb) * invnL[nb + 0];
    o.y = (accS[1] + qb) * invnL[nb + 1];
    o.z = (accS[2] + qb) * invnL[nb + 2];
    o.w = (accS[3] + qb) * invnL[nb + 3];
    *(float4*)&ws[OFF_SCORES + ((b * 3 + m) * 32 + e) * 512 + n0 + nb] = o;
  }

  // probs for this b (only 8 blocks do this)
  if ((bid % 48) == 0) {
    __syncthreads();
    float* st = hsL;
    float* lgS = hsL + 256;
    if (tid < 128) {
      float s = 0.f, q2 = 0.f;
      const float* base = ws + OFF_STATS + b * 32 * 256;
      for (int j = 0; j < 32; ++j) {
        s += base[j * 256 + tid];
        q2 += base[j * 256 + 128 + tid];
      }
      float mean = s * (1.f / 512.f);
      float var = (q2 - 512.f * mean * mean) * (1.f / 511.f);  // ddof=1
      st[tid] = mean;
      st[128 + tid] = sqrtf(fmaxf(var, 0.f));
    }
    __syncthreads();
    if (tid < 3) {
      float acc2 = routerb[tid];
      for (int k = 0; k < 256; ++k) acc2 += st[k] * routerW[tid * 256 + k];
      lgS[tid] = acc2;
    }
    __syncthreads();
    if (tid == 0) {
      float mx = fmaxf(lgS[0], fmaxf(lgS[1], lgS[2]));
      float e0 = expf(lgS[0] - mx), e1 = expf(lgS[1] - mx), e2 = expf(lgS[2] - mx);
      float inv = 1.f / (e0 + e1 + e2);
      ws[OFF_PROBS + b * 3 + 0] = e0 * inv;
      ws[OFF_PROBS + b * 3 + 1] = e1 * inv;
      ws[OFF_PROBS + b * 3 + 2] = e2 * inv;
      d_out[4096 + b * 3 + 0] = e0 * inv;
      d_out[4096 + b * 3 + 1] = e1 * inv;
      d_out[4096 + b * 3 + 2] = e2 * inv;
    }
  }
}

// ---------------------------------------------------------------------------
// topk: 192 blocks x 256 (4 wave-rows). Scatters Hmix AND accumulates ev.
// ---------------------------------------------------------------------------
__global__ __launch_bounds__(256) void topk_kernel(float* __restrict__ ws) {
  const int row0 = blockIdx.x * 4;
  const int b = row0 / 96;
  const int tid = threadIdx.x, wave = tid >> 6, lane = tid & 63;
  __shared__ float hvL[512];
  hvL[tid] = ws[OFF_HV + b * 512 + tid];
  hvL[256 + tid] = ws[OFF_HV + b * 512 + 256 + tid];
  __syncthreads();

  int row = row0 + wave;
  int m = (row / 32) % 3, e = row & 31;
  const float* sc = ws + OFF_SCORES + row * 512;
  float prob = ws[OFF_PROBS + b * 3 + m];

  float v[8];
#pragma unroll
  for (int j = 0; j < 8; ++j) v[j] = sc[j * 64 + lane];

  float selv = 0.f; int seli = 0; float maxv = 0.f;
  for (int it = 0; it < 25; ++it) {
    float bv = v[0]; int bj = 0;
#pragma unroll
    for (int j = 1; j < 8; ++j)
      if (v[j] > bv) { bv = v[j]; bj = j; }
    int bidx = bj * 64 + lane;
    for (int off = 32; off; off >>= 1) {
      float ov = __shfl_xor(bv, off);
      int oi = __shfl_xor(bidx, off);
      if (ov > bv || (ov == bv && oi < bidx)) { bv = ov; bidx = oi; }
    }
    if (lane == (bidx & 63)) v[bidx >> 6] = -INFINITY;
    if (it == 0) maxv = bv;
    if (lane == it) { selv = bv; seli = bidx; }
  }
  float ex = (lane < 25) ? __expf((selv - maxv) * (1.f / 0.7f)) : 0.f;
  float den = ex;
  for (int off = 32; off; off >>= 1) den += __shfl_xor(den, off);
  float w = prob * ex / den;  // 0 for lanes >= 25
  if (lane < 25)
    atomicAdd(&ws[OFF_HMIX + (b * 32 + e) * 512 + seli], w);
  float evc = (lane < 25) ? w * hvL[seli] : 0.f;
  for (int off = 32; off; off >>= 1) evc += __shfl_xor(evc, off);
  if (lane == 0) atomicAdd(&ws[OFF_EV + b * 32 + e], evc);
}

// ---------------------------------------------------------------------------
// final: 128 blocks (b, 32-n chunk) x 512.
// ---------------------------------------------------------------------------
__global__ __launch_bounds__(512) void final_kernel(const float* __restrict__ prior,
                                                    const float* __restrict__ outb,
                                                    const float* __restrict__ plog,
                                                    float* __restrict__ ws,
                                                    float* __restrict__ d_out) {
  const int bid = blockIdx.x;
  const int b = bid >> 4, ch = bid & 15;
  const int tid = threadIdx.x, wave = tid >> 6, lane = tid & 63;
  __shared__ float hvL[512], evL[32];
  hvL[tid] = ws[OFF_HV + b * 512 + tid];
  if (tid < 32) evL[tid] = ws[OFF_EV + b * 32 + tid];
  __syncthreads();
  float alpha = 1.f / (1.f + expf(-plog[0]));
  float ob = outb[0];
#pragma unroll
  for (int i = 0; i < 4; ++i) {
    int n = ch * 32 + wave * 4 + i;
    const float* pr = prior + n * 512;
    float s1 = 0.f;
#pragma unroll
    for (int j = 0; j < 8; ++j) s1 += pr[j * 64 + lane] * hvL[j * 64 + lane];
    float s2 = 0.f;
    if (lane < 32) s2 = ws[OFF_HMIX + (b * 32 + lane) * 512 + n] * evL[lane];
    float a = alpha * s1 + (1.f - alpha) * s2;
    for (int off = 32; off; off >>= 1) a += __shfl_xor(a, off);
    if (lane == 0) d_out[b * 512 + n] = a + ob;
  }
}

// ---------------------------------------------------------------------------
extern "C" void kernel_launch(void* const* d_in, const int* in_sizes, int n_in,
                              void* d_out, int out_size, void* d_ws, size_t ws_size,
                              hipStream_t stream) {
  const float* x       = (const float*)d_in[0];
  const float* prior   = (const float*)d_in[1];
  const float* projW   = (const float*)d_in[2];
  const float* projb   = (const float*)d_in[3];
  const float* Wih     = (const float*)d_in[4];
  const float* Whh     = (const float*)d_in[5];
  const float* bih     = (const float*)d_in[6];
  const float* bhh     = (const float*)d_in[7];
  const float* spaceW  = (const float*)d_in[8];
  const float* spaceb  = (const float*)d_in[9];
  const float* routerW = (const float*)d_in[10];
  const float* routerb = (const float*)d_in[11];
  const float* outW    = (const float*)d_in[12];
  const float* outb    = (const float*)d_in[13];
  const float* plog    = (const float*)d_in[14];
  const float* queries = (const float*)d_in[15];
  float* ws  = (float*)d_ws;
  float* out = (float*)d_out;

  prep_kernel<<<225, 256, 0, stream>>>(Wih, projW, projb, bih, queries, Whh,
                                       spaceW, spaceb, ws);
  gru_kernel<<<256, 512, 0, stream>>>(x, bhh, outW, ws);
  scores_kernel<<<384, 256, 0, stream>>>(spaceb, routerW, routerb, ws, out);
  topk_kernel<<<192, 256, 0, stream>>>(ws);
  final_kernel<<<128, 512, 0, stream>>>(prior, outb, plog, ws, out);
}